// Round 1
// baseline (2081.960 us; speedup 1.0000x reference)
//
#include <hip/hip_runtime.h>
#include <hip/hip_bf16.h>

#define CCH 128
#define BINS 64
#define NCELL (BINS * BINS)

__device__ __forceinline__ void atomicMinF(float* a, float v) {
    if (v >= 0.f) atomicMin((int*)a, __float_as_int(v));
    else          atomicMax((unsigned int*)a, __float_as_uint(v));
}
__device__ __forceinline__ void atomicMaxF(float* a, float v) {
    if (v >= 0.f) atomicMax((int*)a, __float_as_int(v));
    else          atomicMin((unsigned int*)a, __float_as_uint(v));
}

// Zero the grid accumulator, init minmax sentinels.
__global__ void k_init(float* __restrict__ grid, float* __restrict__ minmax) {
    int t = blockIdx.x * blockDim.x + threadIdx.x;
    if (t < NCELL * CCH) grid[t] = 0.f;
    if (t == 0) {
        minmax[0] = INFINITY;  minmax[1] = INFINITY;   // cmin x, y
        minmax[2] = -INFINITY; minmax[3] = -INFINITY;  // cmax x, y
    }
}

// Global min/max of coords (N x 2).
__global__ void k_minmax(const float* __restrict__ coords, int n, float* __restrict__ minmax) {
    float mn0 = INFINITY, mn1 = INFINITY, mx0 = -INFINITY, mx1 = -INFINITY;
    for (int i = blockIdx.x * blockDim.x + threadIdx.x; i < n; i += gridDim.x * blockDim.x) {
        float2 c = ((const float2*)coords)[i];
        mn0 = fminf(mn0, c.x); mx0 = fmaxf(mx0, c.x);
        mn1 = fminf(mn1, c.y); mx1 = fmaxf(mx1, c.y);
    }
    // wave64 reduce
    #pragma unroll
    for (int off = 32; off > 0; off >>= 1) {
        mn0 = fminf(mn0, __shfl_down(mn0, off));
        mn1 = fminf(mn1, __shfl_down(mn1, off));
        mx0 = fmaxf(mx0, __shfl_down(mx0, off));
        mx1 = fmaxf(mx1, __shfl_down(mx1, off));
    }
    if ((threadIdx.x & 63) == 0) {
        atomicMinF(&minmax[0], mn0);
        atomicMinF(&minmax[1], mn1);
        atomicMaxF(&minmax[2], mx0);
        atomicMaxF(&minmax[3], mx1);
    }
}

// Per-point cell index — EXACT op order as reference: (c-cmin)/span, *63, floor, cast, clip.
__global__ void k_cellidx(const float* __restrict__ coords, int n,
                          const float* __restrict__ minmax, int* __restrict__ flat_idx) {
    int i = blockIdx.x * blockDim.x + threadIdx.x;
    if (i >= n) return;
    float c0 = coords[2 * i], c1 = coords[2 * i + 1];
    float cmin0 = minmax[0], cmin1 = minmax[1];
    float span0 = fmaxf(minmax[2] - cmin0, 1e-6f);
    float span1 = fmaxf(minmax[3] - cmin1, 1e-6f);
    float n0 = (c0 - cmin0) / span0;
    float n1 = (c1 - cmin1) / span1;
    int g0 = (int)floorf(n0 * 63.0f);
    int g1 = (int)floorf(n1 * 63.0f);
    g0 = min(max(g0, 0), BINS - 1);
    g1 = min(max(g1, 0), BINS - 1);
    flat_idx[i] = g0 * BINS + g1;
}

// Scatter-add x rows into grid. One thread per (point, 4-channel chunk).
__global__ void k_scatter(const float4* __restrict__ x4, const int* __restrict__ flat_idx,
                          int n, float* __restrict__ grid) {
    long long t = (long long)blockIdx.x * blockDim.x + threadIdx.x;
    int p = (int)(t >> 5);
    int q = (int)(t & 31);
    if (p >= n) return;
    int cell = flat_idx[p];
    float4 v = x4[(long long)p * 32 + q];
    float* dst = grid + cell * CCH + q * 4;
    atomicAdd(dst + 0, v.x);
    atomicAdd(dst + 1, v.y);
    atomicAdd(dst + 2, v.z);
    atomicAdd(dst + 3, v.w);
}

// Depthwise 3x3 SAME conv (cross-correlation, zero pad) + bias.
__global__ void k_conv(const float* __restrict__ grid, const float* __restrict__ dwk,
                       const float* __restrict__ bias, float* __restrict__ out) {
    int t = blockIdx.x * blockDim.x + threadIdx.x;
    if (t >= NCELL * CCH) return;
    int c = t & (CCH - 1);
    int cell = t >> 7;
    int gi = cell >> 6, gj = cell & (BINS - 1);
    float acc = bias[c];
    #pragma unroll
    for (int ki = 0; ki < 3; ki++) {
        int ni = gi + ki - 1;
        if (ni < 0 || ni >= BINS) continue;
        #pragma unroll
        for (int kj = 0; kj < 3; kj++) {
            int nj = gj + kj - 1;
            if (nj < 0 || nj >= BINS) continue;
            acc += grid[((ni << 6) + nj) * CCH + c] * dwk[(ki * 3 + kj) * CCH + c];
        }
    }
    out[t] = acc;
}

// Per-cell pointwise matmul + LayerNorm. One block of 128 threads per cell.
__global__ void __launch_bounds__(CCH) k_pwln(const float* __restrict__ conv,
                                              const float* __restrict__ pww,
                                              const float* __restrict__ pwb,
                                              const float* __restrict__ lns,
                                              const float* __restrict__ lno,
                                              float* __restrict__ cellvec) {
    __shared__ float g[CCH];
    __shared__ float red[CCH];
    int cell = blockIdx.x;
    int j = threadIdx.x;
    g[j] = conv[cell * CCH + j];
    __syncthreads();
    float acc = pwb[j];
    #pragma unroll 8
    for (int k = 0; k < CCH; k++) acc += g[k] * pww[k * CCH + j];

    // mean
    red[j] = acc;
    __syncthreads();
    for (int s = 64; s > 0; s >>= 1) {
        if (j < s) red[j] += red[j + s];
        __syncthreads();
    }
    float mu = red[0] * (1.0f / CCH);
    __syncthreads();

    // variance (two-pass, like numpy)
    float d = acc - mu;
    red[j] = d * d;
    __syncthreads();
    for (int s = 64; s > 0; s >>= 1) {
        if (j < s) red[j] += red[j + s];
        __syncthreads();
    }
    float var = red[0] * (1.0f / CCH);
    float rs = rsqrtf(var + 1e-5f);
    cellvec[cell * CCH + j] = d * rs * lns[j] + lno[j];
}

// Final: out[i] = x[i] + cellvec[cell[i]]. One thread per (point, 4-channel chunk).
__global__ void k_final(const float4* __restrict__ x4, const int* __restrict__ flat_idx,
                        const float4* __restrict__ cellvec4, int n, float4* __restrict__ out4) {
    long long t = (long long)blockIdx.x * blockDim.x + threadIdx.x;
    int p = (int)(t >> 5);
    int q = (int)(t & 31);
    if (p >= n) return;
    int cell = flat_idx[p];
    float4 xv = x4[(long long)p * 32 + q];
    float4 cv = cellvec4[cell * 32 + q];
    out4[(long long)p * 32 + q] = make_float4(xv.x + cv.x, xv.y + cv.y, xv.z + cv.z, xv.w + cv.w);
}

extern "C" void kernel_launch(void* const* d_in, const int* in_sizes, int n_in,
                              void* d_out, int out_size, void* d_ws, size_t ws_size,
                              hipStream_t stream) {
    const float* x      = (const float*)d_in[0];
    const float* coords = (const float*)d_in[1];
    const float* dwk    = (const float*)d_in[2];
    const float* dwb    = (const float*)d_in[3];
    const float* pww    = (const float*)d_in[4];
    const float* pwb    = (const float*)d_in[5];
    const float* lns    = (const float*)d_in[6];
    const float* lno    = (const float*)d_in[7];
    int n = in_sizes[0] / CCH;

    float* grid    = (float*)d_ws;               // NCELL*CCH f32 (2 MB)
    float* conv    = grid + NCELL * CCH;         // 2 MB
    float* cellvec = conv + NCELL * CCH;         // 2 MB
    float* minmax  = cellvec + NCELL * CCH;      // 4 f32
    int*   flat_idx = (int*)(minmax + 4);        // n int32 (4 MB)

    k_init<<<(NCELL * CCH + 255) / 256, 256, 0, stream>>>(grid, minmax);
    k_minmax<<<1024, 256, 0, stream>>>(coords, n, minmax);
    k_cellidx<<<(n + 255) / 256, 256, 0, stream>>>(coords, n, minmax, flat_idx);

    long long tot = (long long)n * 32;
    int blocks = (int)((tot + 255) / 256);
    k_scatter<<<blocks, 256, 0, stream>>>((const float4*)x, flat_idx, n, grid);
    k_conv<<<(NCELL * CCH + 255) / 256, 256, 0, stream>>>(grid, dwk, dwb, conv);
    k_pwln<<<NCELL, CCH, 0, stream>>>(conv, pww, pwb, lns, lno, cellvec);
    k_final<<<blocks, 256, 0, stream>>>((const float4*)x, flat_idx, (const float4*)cellvec, n, (float4*)d_out);
}

// Round 2
// 725.071 us; speedup vs baseline: 2.8714x; 2.8714x over previous
//
#include <hip/hip_runtime.h>
#include <hip/hip_bf16.h>

#define CCH 128
#define BINS 64
#define NCELL (BINS * BINS)

__device__ __forceinline__ void atomicMinF(float* a, float v) {
    if (v >= 0.f) atomicMin((int*)a, __float_as_int(v));
    else          atomicMax((unsigned int*)a, __float_as_uint(v));
}
__device__ __forceinline__ void atomicMaxF(float* a, float v) {
    if (v >= 0.f) atomicMax((int*)a, __float_as_int(v));
    else          atomicMin((unsigned int*)a, __float_as_uint(v));
}

// Init minmax sentinels + zero the 4096-bin histogram.
__global__ void k_init(float* __restrict__ minmax, int* __restrict__ hist) {
    int t = blockIdx.x * blockDim.x + threadIdx.x;
    if (t < NCELL) hist[t] = 0;
    if (t == 0) {
        minmax[0] = INFINITY;  minmax[1] = INFINITY;
        minmax[2] = -INFINITY; minmax[3] = -INFINITY;
    }
}

// Global min/max of coords (N x 2).
__global__ void k_minmax(const float* __restrict__ coords, int n, float* __restrict__ minmax) {
    float mn0 = INFINITY, mn1 = INFINITY, mx0 = -INFINITY, mx1 = -INFINITY;
    for (int i = blockIdx.x * blockDim.x + threadIdx.x; i < n; i += gridDim.x * blockDim.x) {
        float2 c = ((const float2*)coords)[i];
        mn0 = fminf(mn0, c.x); mx0 = fmaxf(mx0, c.x);
        mn1 = fminf(mn1, c.y); mx1 = fmaxf(mx1, c.y);
    }
    #pragma unroll
    for (int off = 32; off > 0; off >>= 1) {
        mn0 = fminf(mn0, __shfl_down(mn0, off));
        mn1 = fminf(mn1, __shfl_down(mn1, off));
        mx0 = fmaxf(mx0, __shfl_down(mx0, off));
        mx1 = fmaxf(mx1, __shfl_down(mx1, off));
    }
    if ((threadIdx.x & 63) == 0) {
        atomicMinF(&minmax[0], mn0);
        atomicMinF(&minmax[1], mn1);
        atomicMaxF(&minmax[2], mx0);
        atomicMaxF(&minmax[3], mx1);
    }
}

// Per-point cell index (exact reference op order) + histogram.
__global__ void k_cellidx(const float* __restrict__ coords, int n,
                          const float* __restrict__ minmax,
                          int* __restrict__ flat_idx, int* __restrict__ hist) {
    int i = blockIdx.x * blockDim.x + threadIdx.x;
    if (i >= n) return;
    float c0 = coords[2 * i], c1 = coords[2 * i + 1];
    float cmin0 = minmax[0], cmin1 = minmax[1];
    float span0 = fmaxf(minmax[2] - cmin0, 1e-6f);
    float span1 = fmaxf(minmax[3] - cmin1, 1e-6f);
    float n0 = (c0 - cmin0) / span0;
    float n1 = (c1 - cmin1) / span1;
    int g0 = (int)floorf(n0 * 63.0f);
    int g1 = (int)floorf(n1 * 63.0f);
    g0 = min(max(g0, 0), BINS - 1);
    g1 = min(max(g1, 0), BINS - 1);
    int cell = g0 * BINS + g1;
    flat_idx[i] = cell;
    atomicAdd(&hist[cell], 1);
}

// Exclusive scan of 4096-bin histogram -> offs[0..4096], cursor copy.
__global__ void __launch_bounds__(256) k_scan(const int* __restrict__ hist,
                                              int* __restrict__ offs, int* __restrict__ cursor) {
    __shared__ int part[256];
    int t = threadIdx.x;
    int local[16];
    int sum = 0;
    #pragma unroll
    for (int i = 0; i < 16; i++) { local[i] = sum; sum += hist[t * 16 + i]; }
    part[t] = sum;
    __syncthreads();
    for (int s = 1; s < 256; s <<= 1) {
        int v = (t >= s) ? part[t - s] : 0;
        __syncthreads();
        part[t] += v;
        __syncthreads();
    }
    int base = (t > 0) ? part[t - 1] : 0;
    #pragma unroll
    for (int i = 0; i < 16; i++) {
        int o = base + local[i];
        offs[t * 16 + i] = o;
        cursor[t * 16 + i] = o;
    }
    if (t == 255) offs[NCELL] = part[255];
}

// Bucket pass: perm[slot] = point index, slot from per-cell cursor.
__global__ void k_bucket(const int* __restrict__ flat_idx, int n,
                         int* __restrict__ cursor, int* __restrict__ perm) {
    int i = blockIdx.x * blockDim.x + threadIdx.x;
    if (i >= n) return;
    int cell = flat_idx[i];
    int slot = atomicAdd(&cursor[cell], 1);
    perm[slot] = i;
}

// Segmented sum: one block per cell, 128 channel-threads x 2 point streams.
__global__ void __launch_bounds__(256) k_cellsum(const float* __restrict__ x,
                                                 const int* __restrict__ perm,
                                                 const int* __restrict__ offs,
                                                 float* __restrict__ grid) {
    __shared__ int idxbuf[256];
    __shared__ float red[128];
    int cell = blockIdx.x;
    int t = threadIdx.x;
    int c = t & 127;
    int s = t >> 7;
    int start = offs[cell], end = offs[cell + 1];
    float acc = 0.f;
    for (int base = start; base < end; base += 256) {
        int m = min(256, end - base);
        if (t < m) idxbuf[t] = perm[base + t];
        __syncthreads();
        for (int i = s; i < m; i += 2)
            acc += x[(long long)idxbuf[i] * CCH + c];
        __syncthreads();
    }
    if (s == 1) red[c] = acc;
    __syncthreads();
    if (s == 0) grid[cell * CCH + c] = acc + red[c];
}

// Depthwise 3x3 SAME conv (cross-correlation, zero pad) + bias.
__global__ void k_conv(const float* __restrict__ grid, const float* __restrict__ dwk,
                       const float* __restrict__ bias, float* __restrict__ out) {
    int t = blockIdx.x * blockDim.x + threadIdx.x;
    if (t >= NCELL * CCH) return;
    int c = t & (CCH - 1);
    int cell = t >> 7;
    int gi = cell >> 6, gj = cell & (BINS - 1);
    float acc = bias[c];
    #pragma unroll
    for (int ki = 0; ki < 3; ki++) {
        int ni = gi + ki - 1;
        if (ni < 0 || ni >= BINS) continue;
        #pragma unroll
        for (int kj = 0; kj < 3; kj++) {
            int nj = gj + kj - 1;
            if (nj < 0 || nj >= BINS) continue;
            acc += grid[((ni << 6) + nj) * CCH + c] * dwk[(ki * 3 + kj) * CCH + c];
        }
    }
    out[t] = acc;
}

// Per-cell pointwise matmul + LayerNorm.
__global__ void __launch_bounds__(CCH) k_pwln(const float* __restrict__ conv,
                                              const float* __restrict__ pww,
                                              const float* __restrict__ pwb,
                                              const float* __restrict__ lns,
                                              const float* __restrict__ lno,
                                              float* __restrict__ cellvec) {
    __shared__ float g[CCH];
    __shared__ float red[CCH];
    int cell = blockIdx.x;
    int j = threadIdx.x;
    g[j] = conv[cell * CCH + j];
    __syncthreads();
    float acc = pwb[j];
    #pragma unroll 8
    for (int k = 0; k < CCH; k++) acc += g[k] * pww[k * CCH + j];

    red[j] = acc;
    __syncthreads();
    for (int s = 64; s > 0; s >>= 1) {
        if (j < s) red[j] += red[j + s];
        __syncthreads();
    }
    float mu = red[0] * (1.0f / CCH);
    __syncthreads();

    float d = acc - mu;
    red[j] = d * d;
    __syncthreads();
    for (int s = 64; s > 0; s >>= 1) {
        if (j < s) red[j] += red[j + s];
        __syncthreads();
    }
    float var = red[0] * (1.0f / CCH);
    float rs = rsqrtf(var + 1e-5f);
    cellvec[cell * CCH + j] = d * rs * lns[j] + lno[j];
}

// Final: out[i] = x[i] + cellvec[cell[i]].
__global__ void k_final(const float4* __restrict__ x4, const int* __restrict__ flat_idx,
                        const float4* __restrict__ cellvec4, int n, float4* __restrict__ out4) {
    long long t = (long long)blockIdx.x * blockDim.x + threadIdx.x;
    int p = (int)(t >> 5);
    int q = (int)(t & 31);
    if (p >= n) return;
    int cell = flat_idx[p];
    float4 xv = x4[(long long)p * 32 + q];
    float4 cv = cellvec4[cell * 32 + q];
    out4[(long long)p * 32 + q] = make_float4(xv.x + cv.x, xv.y + cv.y, xv.z + cv.z, xv.w + cv.w);
}

extern "C" void kernel_launch(void* const* d_in, const int* in_sizes, int n_in,
                              void* d_out, int out_size, void* d_ws, size_t ws_size,
                              hipStream_t stream) {
    const float* x      = (const float*)d_in[0];
    const float* coords = (const float*)d_in[1];
    const float* dwk    = (const float*)d_in[2];
    const float* dwb    = (const float*)d_in[3];
    const float* pww    = (const float*)d_in[4];
    const float* pwb    = (const float*)d_in[5];
    const float* lns    = (const float*)d_in[6];
    const float* lno    = (const float*)d_in[7];
    int n = in_sizes[0] / CCH;

    float* grid     = (float*)d_ws;              // NCELL*CCH f32 (2 MB)
    float* conv     = grid + NCELL * CCH;        // 2 MB
    float* cellvec  = conv + NCELL * CCH;        // 2 MB
    float* minmax   = cellvec + NCELL * CCH;     // 4 f32
    int*   hist     = (int*)(minmax + 4);        // 4096
    int*   offs     = hist + NCELL;              // 4097
    int*   cursor   = offs + NCELL + 1;          // 4096
    int*   flat_idx = cursor + NCELL;            // n int32 (4 MB)
    int*   perm     = flat_idx + n;              // n int32 (4 MB)

    k_init<<<(NCELL + 255) / 256, 256, 0, stream>>>(minmax, hist);
    k_minmax<<<1024, 256, 0, stream>>>(coords, n, minmax);
    k_cellidx<<<(n + 255) / 256, 256, 0, stream>>>(coords, n, minmax, flat_idx, hist);
    k_scan<<<1, 256, 0, stream>>>(hist, offs, cursor);
    k_bucket<<<(n + 255) / 256, 256, 0, stream>>>(flat_idx, n, cursor, perm);
    k_cellsum<<<NCELL, 256, 0, stream>>>(x, perm, offs, grid);
    k_conv<<<(NCELL * CCH + 255) / 256, 256, 0, stream>>>(grid, dwk, dwb, conv);
    k_pwln<<<NCELL, CCH, 0, stream>>>(conv, pww, pwb, lns, lno, cellvec);

    long long tot = (long long)n * 32;
    int blocks = (int)((tot + 255) / 256);
    k_final<<<blocks, 256, 0, stream>>>((const float4*)x, flat_idx, (const float4*)cellvec, n, (float4*)d_out);
}